// Round 2
// baseline (73.938 us; speedup 1.0000x reference)
//
#include <hip/hip_runtime.h>
#include <hip/hip_bf16.h>
#include <math.h>

using short8  = __attribute__((ext_vector_type(8))) short;
using float4v = __attribute__((ext_vector_type(4))) float;

#define D_DIM 1024
#define NCLS  40
#define WSTR  1064          // D + C row stride of padded W
#define TM    64            // rows per block
#define NCHUNK 16           // 1024 / 64

__device__ __forceinline__ short f2bf(float f) {
    // scalar cast — compiler emits the HW cvt (m240: beats hand-written cvt_pk asm)
    __hip_bfloat16 h = __float2bfloat16(f);
    union { __hip_bfloat16 h; short s; } u; u.h = h;
    return u.s;
}

// ---- Kernel 1: pack W / W_rev main parts (cols 0..1023) to bf16 workspace Wb[80][1024]
__global__ void convert_w_kernel(const float* __restrict__ W, const float* __restrict__ Wr,
                                 short* __restrict__ Wb) {
    int idx = blockIdx.x * 256 + threadIdx.x;   // 0..81919
    int c = idx >> 10;                          // 0..79 (0..39 fwd, 40..79 rev)
    int k = idx & 1023;
    float v = (c < NCLS) ? W[c * WSTR + k] : Wr[(c - NCLS) * WSTR + k];
    Wb[idx] = f2bf(v);
}

// ---- Kernel 2: barrier-free streaming GEMM (direct-from-global MFMA fragments)
//                + per-row sequential chain + combine
__global__ __launch_bounds__(256, 2) void bichain_main(
    const float* __restrict__ src, const short* __restrict__ Wb,
    const float* __restrict__ Wf, const float* __restrict__ Wr,
    const float* __restrict__ bf_, const float* __restrict__ br_,
    float* __restrict__ out)
{
    __shared__ float Lg[TM * 81];   // logits, +1 pad stride
    __shared__ float Sc[TM * 80];   // chain scores

    const int tid  = threadIdx.x;
    const int lane = tid & 63;
    const int wave = tid >> 6;
    const int row0 = blockIdx.x * TM;
    const int lrow = lane & 15;          // A row / B class (low 4 bits)
    const int lk8  = (lane >> 4) * 8;    // k octet select

    // A fragment source: row = row0 + wave*16 + lrow, k base = lk8
    // lanes {r, r+16, r+32, r+48} jointly read 128B contiguous of row r -> coalesced
    const float* aRow = src + (size_t)(row0 + wave * 16 + lrow) * D_DIM + lk8;
    // B fragment source: class = t*16 + lrow, k base = lk8 (16B short8 loads, L1/L2-hot)
    const short* wRow = Wb + lrow * D_DIM + lk8;

    float4v acc[5];
#pragma unroll
    for (int t = 0; t < 5; ++t)
#pragma unroll
        for (int r = 0; r < 4; ++r) acc[t][r] = 0.f;

    // 1-chunk-ahead register prefetch of A (64B/lane in flight; no barriers anywhere)
    float4v apre[4];
#pragma unroll
    for (int j = 0; j < 4; ++j)
        apre[j] = *(const float4v*)(aRow + (j >> 1) * 32 + (j & 1) * 4);

#pragma unroll 1
    for (int ch = 0; ch < NCHUNK; ++ch) {
        float4v a[4];
#pragma unroll
        for (int j = 0; j < 4; ++j) a[j] = apre[j];
        if (ch < NCHUNK - 1) {
            const float* nx = aRow + (ch + 1) * 64;
#pragma unroll
            for (int j = 0; j < 4; ++j)
                apre[j] = *(const float4v*)(nx + (j >> 1) * 32 + (j & 1) * 4);
        }
        // convert this chunk's A (16 fp32 -> 2x short8), k = ch*64 + ks*32 + lk8 + e
        short8 af[2];
#pragma unroll
        for (int ks = 0; ks < 2; ++ks)
#pragma unroll
            for (int e = 0; e < 4; ++e) {
                af[ks][e]     = f2bf(a[2 * ks][e]);
                af[ks][e + 4] = f2bf(a[2 * ks + 1][e]);
            }
        const short* wc = wRow + ch * 64;
#pragma unroll
        for (int ks = 0; ks < 2; ++ks)
#pragma unroll
            for (int t = 0; t < 5; ++t) {
                short8 bfr = *(const short8*)(wc + t * 16 * D_DIM + ks * 32);
                acc[t] = __builtin_amdgcn_mfma_f32_16x16x32_bf16(af[ks], bfr, acc[t], 0, 0, 0);
            }
    }

    // ---- logits -> LDS  (C/D layout: col = lane&15, row = (lane>>4)*4 + reg)
#pragma unroll
    for (int t = 0; t < 5; ++t)
#pragma unroll
        for (int r = 0; r < 4; ++r) {
            int row = wave * 16 + (lane >> 4) * 4 + r;
            int cls = t * 16 + (lane & 15);
            Lg[row * 81 + cls] = acc[t][r];
        }
    __syncthreads();

    // ---- sequential chain, fp32, one thread per (row, direction)
    if (tid < 128) {
        const int row = tid >> 1;
        const int dir = tid & 1;
        const float* Wt = dir ? Wr : Wf;
        const float* bi = dir ? br_ : bf_;
        float s[NCLS];
#pragma unroll
        for (int i = 0; i < NCLS; ++i) {
            float z = Lg[row * 81 + dir * NCLS + i] + bi[i];
#pragma unroll
            for (int j = 0; j < i; ++j)
                z += s[j] * Wt[i * WSTR + D_DIM + j];
            s[i] = 1.f / (1.f + __expf(-z));
            Sc[row * 80 + dir * NCLS + i] = s[i];
        }
    }
    __syncthreads();

    // ---- combine + coalesced write: out[:,c] = 0.5*(fwd[c] + rev[39-c])
    float* outp = out + (size_t)row0 * NCLS;
    for (int idx = tid; idx < TM * NCLS; idx += 256) {
        int row = idx / NCLS;
        int c   = idx - row * NCLS;
        outp[idx] = 0.5f * (Sc[row * 80 + c] + Sc[row * 80 + NCLS + (NCLS - 1 - c)]);
    }
}

extern "C" void kernel_launch(void* const* d_in, const int* in_sizes, int n_in,
                              void* d_out, int out_size, void* d_ws, size_t ws_size,
                              hipStream_t stream) {
    const float* src = (const float*)d_in[0];
    // d_in[1] = attn_mask, unused by the reference
    const float* W   = (const float*)d_in[2];
    const float* b   = (const float*)d_in[3];
    const float* Wr  = (const float*)d_in[4];
    const float* br  = (const float*)d_in[5];
    float* out = (float*)d_out;
    short* Wb  = (short*)d_ws;   // 80*1024 bf16 = 160KB scratch

    convert_w_kernel<<<320, 256, 0, stream>>>(W, Wr, Wb);
    bichain_main<<<512, 256, 0, stream>>>(src, Wb, W, Wr, b, br, out);
}

// Round 4
// 45.310 us; speedup vs baseline: 1.6318x; 1.6318x over previous
//
#include <hip/hip_runtime.h>
#include <hip/hip_bf16.h>
#include <math.h>

using short8  = __attribute__((ext_vector_type(8))) short;
using float4v = __attribute__((ext_vector_type(4))) float;

#define D_DIM 1024
#define NCLS  40
#define WSTR  1064          // D + C row stride of padded W
#define TM    64            // rows per block
#define NCHUNK 16           // 1024 / 64 K-chunks

typedef const __attribute__((address_space(1))) void g_void;
typedef __attribute__((address_space(3))) void lds_void;

__device__ __forceinline__ short f2bf(float f) {
    __hip_bfloat16 h = __float2bfloat16(f);
    union { __hip_bfloat16 h; short s; } u; u.h = h;
    return u.s;
}

// ---- Kernel 1: pack W/W_rev main parts into MFMA-fragment-ordered bf16:
//      Wfrag[((ch*2+ks)*5+t)*512 + lane*8 + e]  = class(t*16+lane&15), k=ch*64+ks*32+(lane>>4)*8+e
__global__ void convert_w_kernel(const float* __restrict__ W, const float* __restrict__ Wr,
                                 short* __restrict__ Wfrag) {
    int idx  = blockIdx.x * 256 + threadIdx.x;   // 0..10239 (one short8 each)
    int lane = idx & 63;
    int rest = idx >> 6;          // 0..159  == (ch*2+ks)*5 + t
    int t    = rest % 5;
    int rest2 = rest / 5;
    int ks   = rest2 & 1;
    int ch   = rest2 >> 1;
    int cls  = t * 16 + (lane & 15);
    int k0   = ch * 64 + ks * 32 + (lane >> 4) * 8;
    const float* srow = (cls < NCLS) ? (W + (size_t)cls * WSTR)
                                     : (Wr + (size_t)(cls - NCLS) * WSTR);
    short8 v;
#pragma unroll
    for (int e = 0; e < 8; ++e) v[e] = f2bf(srow[k0 + e]);
    *(short8*)(Wfrag + (size_t)idx * 8) = v;
}

// ---- Kernel 2: gload_lds-staged streaming GEMM + chain + combine
__global__ __launch_bounds__(256, 2) void bichain_main(
    const float* __restrict__ src, const short* __restrict__ Wfrag,
    const float* __restrict__ Wf, const float* __restrict__ Wr,
    const float* __restrict__ bf_, const float* __restrict__ br_,
    float* __restrict__ out)
{
    // LDS: A double buffer 2 x [64 rows][256B] fp32 = 32KB; epilogue reuses as Lg[64][81]
    __shared__ __align__(16) char smem[32768];

    const int tid  = threadIdx.x;
    const int lane = tid & 63;
    const int wave = tid >> 6;
    const int row0 = blockIdx.x * TM;
    const int lrow = lane & 15;
    const int g4   = lane >> 4;          // 0..3

    float4v acc[5];
#pragma unroll
    for (int t = 0; t < 5; ++t)
#pragma unroll
        for (int r = 0; r < 4; ++r) acc[t][r] = 0.f;

    // stage chunk ch of this wave's 16 rows into buf (linear LDS dest, source pre-swizzled)
    auto stage = [&](int ch, int buf) {
        char* dst0 = smem + buf * 16384 + wave * 4096;
#pragma unroll
        for (int j = 0; j < 4; ++j) {
            int r   = wave * 16 + j * 4 + g4;              // tile row this lane feeds
            int j16 = lrow ^ (r & 7);                      // inverse swizzle on source
            const float* gp = src + (size_t)(row0 + r) * D_DIM + ch * 64 + j16 * 4;
            __builtin_amdgcn_global_load_lds((g_void*)gp, (lds_void*)(dst0 + j * 1024),
                                             16, 0, 0);
        }
    };

    stage(0, 0);
    __syncthreads();

#pragma unroll 2
    for (int ch = 0; ch < NCHUNK; ++ch) {
        const int buf = ch & 1;
        // W fragment loads FIRST (so MFMA's W-wait leaves the stage loads in flight)
        short8 wfr[2][5];
#pragma unroll
        for (int ks = 0; ks < 2; ++ks)
#pragma unroll
            for (int t = 0; t < 5; ++t)
                wfr[ks][t] = *(const short8*)(Wfrag +
                                (((size_t)(ch * 2 + ks) * 5 + t) << 9) + (lane << 3));
        if (ch < NCHUNK - 1) stage(ch + 1, buf ^ 1);

        // A fragments from LDS (swizzled 16B slots; conflict-free b128)
        const char* Ab = smem + buf * 16384 + (wave * 16 + lrow) * 256;
#pragma unroll
        for (int ks = 0; ks < 2; ++ks) {
            float4v f0 = *(const float4v*)(Ab + (((ks * 8 + g4 * 2 + 0) ^ (lrow & 7)) << 4));
            float4v f1 = *(const float4v*)(Ab + (((ks * 8 + g4 * 2 + 1) ^ (lrow & 7)) << 4));
            short8 af;
#pragma unroll
            for (int e = 0; e < 4; ++e) { af[e] = f2bf(f0[e]); af[e + 4] = f2bf(f1[e]); }
#pragma unroll
            for (int t = 0; t < 5; ++t)
                acc[t] = __builtin_amdgcn_mfma_f32_16x16x32_bf16(af, wfr[ks][t], acc[t], 0, 0, 0);
        }
        __syncthreads();   // next buffer staged; this buffer's reads drained
    }

    // ---- logits -> LDS  (C/D layout: col = lane&15, row = (lane>>4)*4 + reg)
    float* Lg = (float*)smem;   // [64][81], 20.7KB < 32KB
#pragma unroll
    for (int t = 0; t < 5; ++t)
#pragma unroll
        for (int r = 0; r < 4; ++r) {
            int row = wave * 16 + g4 * 4 + r;
            int cls = t * 16 + lrow;
            Lg[row * 81 + cls] = acc[t][r];
        }
    __syncthreads();

    // ---- sequential chain, fp32, one thread per (row, direction); scores in-place
    if (tid < 128) {
        const int row = tid >> 1;
        const int dir = tid & 1;
        const float* Wt = dir ? Wr : Wf;
        const float* bi = dir ? br_ : bf_;
        float s[NCLS];
#pragma unroll
        for (int i = 0; i < NCLS; ++i) {
            float z = Lg[row * 81 + dir * NCLS + i] + bi[i];
#pragma unroll
            for (int j = 0; j < i; ++j)
                z += s[j] * Wt[i * WSTR + D_DIM + j];
            s[i] = 1.f / (1.f + __expf(-z));
            Lg[row * 81 + dir * NCLS + i] = s[i];   // overwrite logit with score
        }
    }
    __syncthreads();

    // ---- combine + coalesced write: out[:,c] = 0.5*(fwd[c] + rev[39-c])
    float* outp = out + (size_t)row0 * NCLS;
    for (int idx = tid; idx < TM * NCLS; idx += 256) {
        int row = idx / NCLS;
        int c   = idx - row * NCLS;
        outp[idx] = 0.5f * (Lg[row * 81 + c] + Lg[row * 81 + NCLS + (NCLS - 1 - c)]);
    }
}

extern "C" void kernel_launch(void* const* d_in, const int* in_sizes, int n_in,
                              void* d_out, int out_size, void* d_ws, size_t ws_size,
                              hipStream_t stream) {
    const float* src = (const float*)d_in[0];
    // d_in[1] = attn_mask, unused by the reference
    const float* W   = (const float*)d_in[2];
    const float* b   = (const float*)d_in[3];
    const float* Wr  = (const float*)d_in[4];
    const float* br  = (const float*)d_in[5];
    float* out = (float*)d_out;
    short* Wfrag = (short*)d_ws;   // 160KB fragment-ordered bf16 weights

    convert_w_kernel<<<40, 256, 0, stream>>>(W, Wr, Wfrag);
    bichain_main<<<512, 256, 0, stream>>>(src, Wfrag, W, Wr, b, br, out);
}

// Round 5
// 44.252 us; speedup vs baseline: 1.6708x; 1.0239x over previous
//
#include <hip/hip_runtime.h>
#include <hip/hip_bf16.h>
#include <math.h>

using short8  = __attribute__((ext_vector_type(8))) short;
using float4v = __attribute__((ext_vector_type(4))) float;

#define D_DIM 1024
#define NCLS  40
#define WSTR  1064          // D + C row stride of padded W
#define TM    64            // rows per block
#define NCHUNK 16           // 1024 / 64 K-chunks

typedef const __attribute__((address_space(1))) void g_void;
typedef __attribute__((address_space(3))) void lds_void;

__device__ __forceinline__ short f2bf(float f) {
    __hip_bfloat16 h = __float2bfloat16(f);
    union { __hip_bfloat16 h; short s; } u; u.h = h;
    return u.s;
}

// ---- Kernel 1: pack W/W_rev main parts into MFMA-fragment-ordered bf16:
//      Wfrag[((ch*2+ks)*5+t)*512 + lane*8 + e]  = class(t*16+lane&15), k=ch*64+ks*32+(lane>>4)*8+e
__global__ void convert_w_kernel(const float* __restrict__ W, const float* __restrict__ Wr,
                                 short* __restrict__ Wfrag) {
    int idx  = blockIdx.x * 256 + threadIdx.x;   // 0..10239 (one short8 each)
    int lane = idx & 63;
    int rest = idx >> 6;          // 0..159  == (ch*2+ks)*5 + t
    int t    = rest % 5;
    int rest2 = rest / 5;
    int ks   = rest2 & 1;
    int ch   = rest2 >> 1;
    int cls  = t * 16 + (lane & 15);
    int k0   = ch * 64 + ks * 32 + (lane >> 4) * 8;
    const float* srow = (cls < NCLS) ? (W + (size_t)cls * WSTR)
                                     : (Wr + (size_t)(cls - NCLS) * WSTR);
    short8 v;
#pragma unroll
    for (int e = 0; e < 8; ++e) v[e] = f2bf(srow[k0 + e]);
    *(short8*)(Wfrag + (size_t)idx * 8) = v;
}

// ---- Kernel 2: barrier-free K-loop (per-wave counted vmcnt, T4) + chain + combine
__global__ __launch_bounds__(256, 2) void bichain_main(
    const float* __restrict__ src, const short* __restrict__ Wfrag,
    const float* __restrict__ Wf, const float* __restrict__ Wr,
    const float* __restrict__ bf_, const float* __restrict__ br_,
    float* __restrict__ out)
{
    // LDS: A triple buffer 3 x [64 rows][256B] fp32 = 48KB; epilogue reuses as Lg[64][81]
    __shared__ __align__(16) char smem[49152];

    const int tid  = threadIdx.x;
    const int lane = tid & 63;
    const int wave = tid >> 6;
    const int row0 = blockIdx.x * TM;
    const int lrow = lane & 15;
    const int g4   = lane >> 4;          // 0..3

    float4v acc[5];
#pragma unroll
    for (int t = 0; t < 5; ++t)
#pragma unroll
        for (int r = 0; r < 4; ++r) acc[t][r] = 0.f;

    // stage chunk ch of this wave's 16 rows into buf (linear LDS dest, source pre-swizzled)
    // exactly 4 global_load_lds per wave per call — the vmcnt(8) anchor counts on this
    auto stage = [&](int ch, int buf) {
        char* dst0 = smem + buf * 16384 + wave * 4096;
#pragma unroll
        for (int j = 0; j < 4; ++j) {
            int r   = wave * 16 + j * 4 + g4;              // tile row this lane feeds
            int j16 = lrow ^ (r & 7);                      // inverse swizzle on source
            const float* gp = src + (size_t)(row0 + r) * D_DIM + ch * 64 + j16 * 4;
            __builtin_amdgcn_global_load_lds((g_void*)gp, (lds_void*)(dst0 + j * 1024),
                                             16, 0, 0);
        }
    };

    // prologue: stage chunks 0 and 1 (depth-2 pipeline), no waits
    stage(0, 0);
    stage(1, 1);

    int bcur = 0;
#pragma unroll 1
    for (int ch = 0; ch < NCHUNK; ++ch) {
        // W fragment loads (coalesced 1KB/wave from L1/L2-hot Wfrag; compiler waits on use)
        short8 wfr[2][5];
#pragma unroll
        for (int ks = 0; ks < 2; ++ks)
#pragma unroll
            for (int t = 0; t < 5; ++t)
                wfr[ks][t] = *(const short8*)(Wfrag +
                                (((size_t)(ch * 2 + ks) * 5 + t) << 9) + (lane << 3));
        // stage ch+2 two chunks ahead
        int bnxt2 = bcur + 2; if (bnxt2 >= 3) bnxt2 -= 3;
        if (ch < NCHUNK - 2) stage(ch + 2, bnxt2);

        // T4 anchor: wait until at most 8 VMEM ops outstanding. stage(ch) has >=8
        // younger ops (stage(ch+1) x4 + stage(ch+2) x4), so buf[bcur] is landed.
        // Never drains to 0 -> the two next chunks stay in flight.
        asm volatile("s_waitcnt vmcnt(8)" ::: "memory");
        __builtin_amdgcn_sched_barrier(0);

        // A fragments from LDS (swizzled 16B slots; conflict-free b128)
        const char* Ab = smem + bcur * 16384 + (wave * 16 + lrow) * 256;
#pragma unroll
        for (int ks = 0; ks < 2; ++ks) {
            float4v f0 = *(const float4v*)(Ab + (((ks * 8 + g4 * 2 + 0) ^ (lrow & 7)) << 4));
            float4v f1 = *(const float4v*)(Ab + (((ks * 8 + g4 * 2 + 1) ^ (lrow & 7)) << 4));
            short8 af;
#pragma unroll
            for (int e = 0; e < 4; ++e) { af[e] = f2bf(f0[e]); af[e + 4] = f2bf(f1[e]); }
#pragma unroll
            for (int t = 0; t < 5; ++t)
                acc[t] = __builtin_amdgcn_mfma_f32_16x16x32_bf16(af, wfr[ks][t], acc[t], 0, 0, 0);
        }
        bcur = bcur + 1; if (bcur >= 3) bcur -= 3;
    }

    __syncthreads();   // single full drain: all waves' LDS reads done before smem reuse

    // ---- logits -> LDS  (C/D layout: col = lane&15, row = (lane>>4)*4 + reg)
    float* Lg = (float*)smem;   // [64][81], 20.7KB < 48KB
#pragma unroll
    for (int t = 0; t < 5; ++t)
#pragma unroll
        for (int r = 0; r < 4; ++r) {
            int row = wave * 16 + g4 * 4 + r;
            int cls = t * 16 + lrow;
            Lg[row * 81 + cls] = acc[t][r];
        }
    __syncthreads();

    // ---- sequential chain, fp32, one thread per (row, direction); scores in-place
    if (tid < 128) {
        const int row = tid >> 1;
        const int dir = tid & 1;
        const float* Wt = dir ? Wr : Wf;
        const float* bi = dir ? br_ : bf_;
        float s[NCLS];
#pragma unroll
        for (int i = 0; i < NCLS; ++i) {
            float z = Lg[row * 81 + dir * NCLS + i] + bi[i];
#pragma unroll
            for (int j = 0; j < i; ++j)
                z += s[j] * Wt[i * WSTR + D_DIM + j];
            s[i] = 1.f / (1.f + __expf(-z));
            Lg[row * 81 + dir * NCLS + i] = s[i];   // overwrite logit with score
        }
    }
    __syncthreads();

    // ---- combine + coalesced write: out[:,c] = 0.5*(fwd[c] + rev[39-c])
    float* outp = out + (size_t)row0 * NCLS;
    for (int idx = tid; idx < TM * NCLS; idx += 256) {
        int row = idx / NCLS;
        int c   = idx - row * NCLS;
        outp[idx] = 0.5f * (Lg[row * 81 + c] + Lg[row * 81 + NCLS + (NCLS - 1 - c)]);
    }
}

extern "C" void kernel_launch(void* const* d_in, const int* in_sizes, int n_in,
                              void* d_out, int out_size, void* d_ws, size_t ws_size,
                              hipStream_t stream) {
    const float* src = (const float*)d_in[0];
    // d_in[1] = attn_mask, unused by the reference
    const float* W   = (const float*)d_in[2];
    const float* b   = (const float*)d_in[3];
    const float* Wr  = (const float*)d_in[4];
    const float* br  = (const float*)d_in[5];
    float* out = (float*)d_out;
    short* Wfrag = (short*)d_ws;   // 160KB fragment-ordered bf16 weights

    convert_w_kernel<<<40, 256, 0, stream>>>(W, Wr, Wfrag);
    bichain_main<<<512, 256, 0, stream>>>(src, Wfrag, W, Wr, b, br, out);
}

// Round 6
// 43.328 us; speedup vs baseline: 1.7065x; 1.0213x over previous
//
#include <hip/hip_runtime.h>
#include <hip/hip_bf16.h>
#include <math.h>

using short8   = __attribute__((ext_vector_type(8))) short;
using ushort4v = __attribute__((ext_vector_type(4))) unsigned short;
using float4v  = __attribute__((ext_vector_type(4))) float;

#define D_DIM 1024
#define NCLS  40
#define WSTR  1064
#define TM    64
#define NCH   16            // 1024 / 64 K-chunks

__device__ __forceinline__ short f2bf(float f) {
    __hip_bfloat16 h = __float2bfloat16(f);
    union { __hip_bfloat16 h; short s; } u; u.h = h;
    return u.s;
}

// ---- Kernel 1: pack W/W_rev into MFMA-fragment order (unchanged, verified):
//      Wfrag[((ch*2+ks)*5+t)*512 + lane*8 + e] = class(t*16+lane&15), k=ch*64+ks*32+(lane>>4)*8+e
__global__ void convert_w_kernel(const float* __restrict__ W, const float* __restrict__ Wr,
                                 short* __restrict__ Wfrag) {
    int idx  = blockIdx.x * 256 + threadIdx.x;
    int lane = idx & 63;
    int rest = idx >> 6;
    int t    = rest % 5;
    int rest2 = rest / 5;
    int ks   = rest2 & 1;
    int ch   = rest2 >> 1;
    int cls  = t * 16 + (lane & 15);
    int k0   = ch * 64 + ks * 32 + (lane >> 4) * 8;
    const float* srow = (cls < NCLS) ? (W + (size_t)cls * WSTR)
                                     : (Wr + (size_t)(cls - NCLS) * WSTR);
    short8 v;
#pragma unroll
    for (int e = 0; e < 8; ++e) v[e] = f2bf(srow[k0 + e]);
    *(short8*)(Wfrag + (size_t)idx * 8) = v;
}

// ---- Kernel 2: barrier-free, register-staged, software-pipelined GEMM + chain
__global__ __launch_bounds__(256, 2) void bichain_main(
    const float* __restrict__ src, const short* __restrict__ Wfrag,
    const float* __restrict__ Wf, const float* __restrict__ Wr,
    const float* __restrict__ bf_, const float* __restrict__ br_,
    float* __restrict__ out)
{
    // LDS: per-wave-private bf16 A tiles: 4 waves x 3 bufs x [16 rows][128B] = 24KB
    // epilogue reuses as Lg[64][81] fp32 (20.7KB)
    __shared__ __align__(16) char smem[24576];

    const int tid  = threadIdx.x;
    const int lane = tid & 63;
    const int wave = tid >> 6;
    const int row0 = blockIdx.x * TM;
    const int i16  = lane & 15;      // load: col quad | frag: A row
    const int i4   = lane >> 4;      // load: row-in-quad | frag: k octet

    char* ldsW = smem + wave * 6144;           // this wave's 3 buffers
    // A global base: coalesced — per instr 4 rows x 256B contiguous segments
    const float* aGlob = src + (size_t)(row0 + wave * 16 + i4) * D_DIM + i16 * 4;

    float4v ap[3][4];      // pending A chunks (slot = ch%3, static idx via macros)
    short8  wp[2][10];     // pending W fragments (slot = ch%2)
    float4v acc[5];
#pragma unroll
    for (int t = 0; t < 5; ++t)
#pragma unroll
        for (int r = 0; r < 4; ++r) acc[t][r] = 0.f;

#define LOADA(ch) do { if ((ch) < NCH) {                                   \
    const float* _p = aGlob + (ch) * 64;                                   \
    ap[(ch)%3][0] = *(const float4v*)(_p);                                 \
    ap[(ch)%3][1] = *(const float4v*)(_p + 4 * D_DIM);                     \
    ap[(ch)%3][2] = *(const float4v*)(_p + 8 * D_DIM);                     \
    ap[(ch)%3][3] = *(const float4v*)(_p + 12 * D_DIM); } } while (0)

#define LOADW(ch) do { if ((ch) < NCH) {                                   \
    const short* _w = Wfrag + (size_t)(ch) * 5120 + (lane << 3);           \
    wp[(ch)%2][0] = *(const short8*)(_w + 0 * 512);                        \
    wp[(ch)%2][1] = *(const short8*)(_w + 1 * 512);                        \
    wp[(ch)%2][2] = *(const short8*)(_w + 2 * 512);                        \
    wp[(ch)%2][3] = *(const short8*)(_w + 3 * 512);                        \
    wp[(ch)%2][4] = *(const short8*)(_w + 4 * 512);                        \
    wp[(ch)%2][5] = *(const short8*)(_w + 5 * 512);                        \
    wp[(ch)%2][6] = *(const short8*)(_w + 6 * 512);                        \
    wp[(ch)%2][7] = *(const short8*)(_w + 7 * 512);                        \
    wp[(ch)%2][8] = *(const short8*)(_w + 8 * 512);                        \
    wp[(ch)%2][9] = *(const short8*)(_w + 9 * 512); } } while (0)

// cvt fp32->bf16 + swizzled ds_write_b64 (8B slot XOR: slot' = i16 ^ ((row&7)<<1))
#define DSW1(ch, j) {                                                      \
    int _r = (j) * 4 + i4;                                                 \
    ushort4v _v;                                                           \
    _v[0] = (unsigned short)f2bf(ap[(ch)%3][j][0]);                        \
    _v[1] = (unsigned short)f2bf(ap[(ch)%3][j][1]);                        \
    _v[2] = (unsigned short)f2bf(ap[(ch)%3][j][2]);                        \
    _v[3] = (unsigned short)f2bf(ap[(ch)%3][j][3]);                        \
    *(ushort4v*)(_b + _r * 128 + ((i16 ^ ((_r & 7) << 1)) << 3)) = _v; }
#define DSW(ch) do { if ((ch) < NCH) {                                     \
    char* _b = ldsW + ((ch)%3) * 2048;                                     \
    DSW1(ch, 0) DSW1(ch, 1) DSW1(ch, 2) DSW1(ch, 3) } } while (0)

// fragment reads (swizzled, conflict-free b128) + 10 MFMA
#define MFMA_(ch) do {                                                     \
    const char* _fb = ldsW + ((ch)%3) * 2048 + i16 * 128;                  \
    const int _sw = (i16 & 7) << 1;                                        \
    short8 _a0 = *(const short8*)(_fb + (((i4 * 2)     ^ _sw) << 3));      \
    acc[0] = __builtin_amdgcn_mfma_f32_16x16x32_bf16(_a0, wp[(ch)%2][0], acc[0], 0, 0, 0); \
    acc[1] = __builtin_amdgcn_mfma_f32_16x16x32_bf16(_a0, wp[(ch)%2][1], acc[1], 0, 0, 0); \
    acc[2] = __builtin_amdgcn_mfma_f32_16x16x32_bf16(_a0, wp[(ch)%2][2], acc[2], 0, 0, 0); \
    acc[3] = __builtin_amdgcn_mfma_f32_16x16x32_bf16(_a0, wp[(ch)%2][3], acc[3], 0, 0, 0); \
    acc[4] = __builtin_amdgcn_mfma_f32_16x16x32_bf16(_a0, wp[(ch)%2][4], acc[4], 0, 0, 0); \
    short8 _a1 = *(const short8*)(_fb + (((8 + i4 * 2) ^ _sw) << 3));      \
    acc[0] = __builtin_amdgcn_mfma_f32_16x16x32_bf16(_a1, wp[(ch)%2][5], acc[0], 0, 0, 0); \
    acc[1] = __builtin_amdgcn_mfma_f32_16x16x32_bf16(_a1, wp[(ch)%2][6], acc[1], 0, 0, 0); \
    acc[2] = __builtin_amdgcn_mfma_f32_16x16x32_bf16(_a1, wp[(ch)%2][7], acc[2], 0, 0, 0); \
    acc[3] = __builtin_amdgcn_mfma_f32_16x16x32_bf16(_a1, wp[(ch)%2][8], acc[3], 0, 0, 0); \
    acc[4] = __builtin_amdgcn_mfma_f32_16x16x32_bf16(_a1, wp[(ch)%2][9], acc[4], 0, 0, 0); \
  } while (0)

// body ch: W(ch+1) first (so MFMA's W-wait never drains younger A loads — vmcnt FIFO),
// then A(ch+3) issue, then cvt+ds_write(ch+1) [regs 2 bodies old], then compute ch.
#define BODY(ch) do { LOADW((ch)+1); LOADA((ch)+3); DSW((ch)+1); MFMA_(ch); } while (0)

    // prologue: 3 A chunks + 1 W chunk in flight, chunk 0 staged
    LOADA(0); LOADA(1); LOADA(2); LOADW(0); DSW(0);
    BODY(0);  BODY(1);  BODY(2);  BODY(3);
    BODY(4);  BODY(5);  BODY(6);  BODY(7);
    BODY(8);  BODY(9);  BODY(10); BODY(11);
    BODY(12); BODY(13); BODY(14); BODY(15);

#undef LOADA
#undef LOADW
#undef DSW1
#undef DSW
#undef MFMA_
#undef BODY

    __syncthreads();   // all waves done with private LDS before reuse

    // ---- logits -> LDS  (C/D layout: col = lane&15, row = (lane>>4)*4 + reg)
    float* Lg = (float*)smem;   // [64][81]
#pragma unroll
    for (int t = 0; t < 5; ++t)
#pragma unroll
        for (int r = 0; r < 4; ++r) {
            int row = wave * 16 + i4 * 4 + r;
            int cls = t * 16 + i16;
            Lg[row * 81 + cls] = acc[t][r];
        }
    __syncthreads();

    // ---- sequential chain, fp32, one thread per (row, direction); scores in-place
    if (tid < 128) {
        const int row = tid >> 1;
        const int dir = tid & 1;
        const float* Wt = dir ? Wr : Wf;
        const float* bi = dir ? br_ : bf_;
        float s[NCLS];
#pragma unroll
        for (int i = 0; i < NCLS; ++i) {
            float z = Lg[row * 81 + dir * NCLS + i] + bi[i];
#pragma unroll
            for (int j = 0; j < i; ++j)
                z += s[j] * Wt[i * WSTR + D_DIM + j];
            s[i] = 1.f / (1.f + __expf(-z));
            Lg[row * 81 + dir * NCLS + i] = s[i];
        }
    }
    __syncthreads();

    // ---- combine + coalesced write: out[:,c] = 0.5*(fwd[c] + rev[39-c])
    float* outp = out + (size_t)row0 * NCLS;
    for (int idx = tid; idx < TM * NCLS; idx += 256) {
        int row = idx / NCLS;
        int c   = idx - row * NCLS;
        outp[idx] = 0.5f * (Lg[row * 81 + c] + Lg[row * 81 + NCLS + (NCLS - 1 - c)]);
    }
}

extern "C" void kernel_launch(void* const* d_in, const int* in_sizes, int n_in,
                              void* d_out, int out_size, void* d_ws, size_t ws_size,
                              hipStream_t stream) {
    const float* src = (const float*)d_in[0];
    // d_in[1] = attn_mask, unused by the reference
    const float* W   = (const float*)d_in[2];
    const float* b   = (const float*)d_in[3];
    const float* Wr  = (const float*)d_in[4];
    const float* br  = (const float*)d_in[5];
    float* out = (float*)d_out;
    short* Wfrag = (short*)d_ws;   // 160KB fragment-ordered bf16 weights

    convert_w_kernel<<<40, 256, 0, stream>>>(W, Wr, Wfrag);
    bichain_main<<<512, 256, 0, stream>>>(src, Wfrag, W, Wr, b, br, out);
}